// Round 18
// baseline (3118.915 us; speedup 1.0000x reference)
//
#include <hip/hip_runtime.h>
#include <hip/hip_bf16.h>

#define LNUM 128
#define NNODES 30000
#define NEDGES 150000
#define NSTEPS 5

// NOTE (r17 discovery): d_out is FLOAT32 (reference is pure jnp.float32).
// All rounds 2-16 wrote bf16 into the f32 buffer -> scrambled comparison.

// ---------------------------------------------------------------------------
// MLP core: xs[ROWS][KP] in LDS -> LN(relu(relu(x@W1+b1)@W2+b2))*g+be.
// One output feature per thread, ROWS rows per 128-thread workgroup.
// Weights f32, k-major: W[k*128 + t] (coalesced across t).
// ---------------------------------------------------------------------------
template<int ROWS, int K, int KP>
__device__ __forceinline__ void mlp_apply(
    const float* __restrict__ xs, float* __restrict__ hv,
    float* __restrict__ mu_s, float* __restrict__ rs_s,
    const float* __restrict__ W1, const float* __restrict__ b1,
    const float* __restrict__ W2, const float* __restrict__ b2,
    const float* __restrict__ g,  const float* __restrict__ be,
    float out[ROWS])
{
    const int t = threadIdx.x;
    float acc[ROWS];
    {
        const float bb = b1[t];
        #pragma unroll
        for (int r = 0; r < ROWS; r++) acc[r] = bb;
    }
    int k = 0;
    for (; k + 4 <= K; k += 4) {
        const float w0 = W1[(k + 0) * LNUM + t];
        const float w1 = W1[(k + 1) * LNUM + t];
        const float w2 = W1[(k + 2) * LNUM + t];
        const float w3 = W1[(k + 3) * LNUM + t];
        #pragma unroll
        for (int r = 0; r < ROWS; r++) {
            const float4 x = *(const float4*)(xs + r * KP + k);
            acc[r] = fmaf(x.x, w0, acc[r]);
            acc[r] = fmaf(x.y, w1, acc[r]);
            acc[r] = fmaf(x.z, w2, acc[r]);
            acc[r] = fmaf(x.w, w3, acc[r]);
        }
    }
    for (; k < K; ++k) {
        const float w = W1[k * LNUM + t];
        #pragma unroll
        for (int r = 0; r < ROWS; r++) acc[r] = fmaf(xs[r * KP + k], w, acc[r]);
    }
    #pragma unroll
    for (int r = 0; r < ROWS; r++) hv[r * LNUM + t] = fmaxf(acc[r], 0.f);
    __syncthreads();
    {
        const float bb = b2[t];
        #pragma unroll
        for (int r = 0; r < ROWS; r++) acc[r] = bb;
    }
    for (int k2 = 0; k2 < LNUM; k2 += 4) {
        const float w0 = W2[(k2 + 0) * LNUM + t];
        const float w1 = W2[(k2 + 1) * LNUM + t];
        const float w2 = W2[(k2 + 2) * LNUM + t];
        const float w3 = W2[(k2 + 3) * LNUM + t];
        #pragma unroll
        for (int r = 0; r < ROWS; r++) {
            const float4 x = *(const float4*)(hv + r * LNUM + k2);
            acc[r] = fmaf(x.x, w0, acc[r]);
            acc[r] = fmaf(x.y, w1, acc[r]);
            acc[r] = fmaf(x.z, w2, acc[r]);
            acc[r] = fmaf(x.w, w3, acc[r]);
        }
    }
    __syncthreads();
    #pragma unroll
    for (int r = 0; r < ROWS; r++) hv[r * LNUM + t] = fmaxf(acc[r], 0.f);
    __syncthreads();
    if (t < ROWS) {
        float s = 0.f, s2 = 0.f;
        for (int kk = 0; kk < LNUM; kk++) {
            const float v = hv[t * LNUM + kk];
            s += v; s2 += v * v;
        }
        const float m = s * (1.0f / LNUM);
        mu_s[t] = m;
        rs_s[t] = rsqrtf(fmaxf(s2 * (1.0f / LNUM) - m * m, 0.f) + 1e-5f);
    }
    __syncthreads();
    const float gg = g[t], bbe = be[t];
    #pragma unroll
    for (int r = 0; r < ROWS; r++)
        out[r] = fmaf(gg * (hv[r * LNUM + t] - mu_s[r]), rs_s[r], bbe);
}

__global__ __launch_bounds__(128) void encode_nodes_k(
    const float* __restrict__ u, const float* __restrict__ load_,
    const float* __restrict__ ntype,
    const float* __restrict__ W1, const float* __restrict__ b1,
    const float* __restrict__ W2, const float* __restrict__ b2,
    const float* __restrict__ g,  const float* __restrict__ be,
    float* __restrict__ nl)
{
    constexpr int ROWS = 4, K = 12, KP = 12;
    __shared__ __align__(16) float xs[ROWS * KP];
    __shared__ __align__(16) float hv[ROWS * LNUM];
    __shared__ float mu_s[ROWS], rs_s[ROWS];
    const int t = threadIdx.x;
    const int base = blockIdx.x * ROWS;
    if (t < ROWS * K) {
        const int r = t / K, k = t % K;
        const int n = base + r;
        float v;
        if (k < 2)      v = u[n * 2 + k];
        else if (k < 3) v = load_[n];
        else            v = ntype[n * 9 + (k - 3)];
        xs[r * KP + k] = v;
    }
    __syncthreads();
    float out[ROWS];
    mlp_apply<ROWS, K, KP>(xs, hv, mu_s, rs_s, W1, b1, W2, b2, g, be, out);
    #pragma unroll
    for (int r = 0; r < ROWS; r++) nl[(base + r) * LNUM + t] = out[r];
}

__global__ __launch_bounds__(128) void encode_edges_k(
    const float* __restrict__ mesh_pos, const float* __restrict__ u,
    const int* __restrict__ senders, const int* __restrict__ receivers,
    const float* __restrict__ W1, const float* __restrict__ b1,
    const float* __restrict__ W2, const float* __restrict__ b2,
    const float* __restrict__ g,  const float* __restrict__ be,
    float* __restrict__ el)
{
    constexpr int ROWS = 4, K = 5, KP = 8;
    __shared__ __align__(16) float xs[ROWS * KP];
    __shared__ __align__(16) float hv[ROWS * LNUM];
    __shared__ float mu_s[ROWS], rs_s[ROWS];
    const int t = threadIdx.x;
    const int base = blockIdx.x * ROWS;
    if (t < ROWS) {
        const int e = base + t;
        const int s = senders[e], rcv = receivers[e];
        const float rx = mesh_pos[s * 2 + 0] - mesh_pos[rcv * 2 + 0];
        const float ry = mesh_pos[s * 2 + 1] - mesh_pos[rcv * 2 + 1];
        const float d  = sqrtf(rx * rx + ry * ry);
        const float g0 = u[s * 2 + 0] - u[rcv * 2 + 0];
        const float g1 = u[s * 2 + 1] - u[rcv * 2 + 1];
        float* row = xs + t * KP;
        row[0] = rx; row[1] = ry; row[2] = d; row[3] = g0; row[4] = g1;
        row[5] = 0.f; row[6] = 0.f; row[7] = 0.f;
    }
    __syncthreads();
    float out[ROWS];
    mlp_apply<ROWS, K, KP>(xs, hv, mu_s, rs_s, W1, b1, W2, b2, g, be, out);
    #pragma unroll
    for (int r = 0; r < ROWS; r++) el[(size_t)(base + r) * LNUM + t] = out[r];
}

__global__ __launch_bounds__(128) void block_edge_k(
    const float* __restrict__ nl, float* __restrict__ el,
    float* __restrict__ aggr,
    const int* __restrict__ senders, const int* __restrict__ receivers,
    const float* __restrict__ W1, const float* __restrict__ b1,
    const float* __restrict__ W2, const float* __restrict__ b2,
    const float* __restrict__ g,  const float* __restrict__ be)
{
    constexpr int ROWS = 4, K = 3 * LNUM, KP = 3 * LNUM;
    __shared__ __align__(16) float xs[ROWS * KP];
    __shared__ __align__(16) float hv[ROWS * LNUM];
    __shared__ float mu_s[ROWS], rs_s[ROWS];
    __shared__ int sidx[ROWS], ridx[ROWS];
    const int t = threadIdx.x;
    const int base = blockIdx.x * ROWS;
    if (t < ROWS) { sidx[t] = senders[base + t]; ridx[t] = receivers[base + t]; }
    __syncthreads();
    #pragma unroll
    for (int r = 0; r < ROWS; r++) {
        const int e = base + r;
        xs[r * KP + t]            = nl[sidx[r] * LNUM + t];
        xs[r * KP + LNUM + t]     = nl[ridx[r] * LNUM + t];
        xs[r * KP + 2 * LNUM + t] = el[(size_t)e * LNUM + t];
    }
    __syncthreads();
    float out[ROWS];
    mlp_apply<ROWS, K, KP>(xs, hv, mu_s, rs_s, W1, b1, W2, b2, g, be, out);
    #pragma unroll
    for (int r = 0; r < ROWS; r++) {
        const int e = base + r;
        const float ne = out[r];
        el[(size_t)e * LNUM + t] = xs[r * KP + 2 * LNUM + t] + ne;  // residual
        atomicAdd(&aggr[ridx[r] * LNUM + t], ne);                   // segment_sum
    }
}

__global__ __launch_bounds__(128) void block_node_k(
    float* __restrict__ nl, const float* __restrict__ aggr,
    const float* __restrict__ W1, const float* __restrict__ b1,
    const float* __restrict__ W2, const float* __restrict__ b2,
    const float* __restrict__ g,  const float* __restrict__ be)
{
    constexpr int ROWS = 4, K = 2 * LNUM, KP = 2 * LNUM;
    __shared__ __align__(16) float xs[ROWS * KP];
    __shared__ __align__(16) float hv[ROWS * LNUM];
    __shared__ float mu_s[ROWS], rs_s[ROWS];
    const int t = threadIdx.x;
    const int base = blockIdx.x * ROWS;
    #pragma unroll
    for (int r = 0; r < ROWS; r++) {
        const int n = base + r;
        xs[r * KP + t]        = nl[n * LNUM + t];
        xs[r * KP + LNUM + t] = aggr[n * LNUM + t];
    }
    __syncthreads();
    float out[ROWS];
    mlp_apply<ROWS, K, KP>(xs, hv, mu_s, rs_s, W1, b1, W2, b2, g, be, out);
    #pragma unroll
    for (int r = 0; r < ROWS; r++) {
        const int n = base + r;
        nl[n * LNUM + t] = xs[r * KP + t] + out[r];          // residual
    }
}

// Decoder -> FLOAT32 output, layout [TW, N, TD].
__global__ __launch_bounds__(128) void decode_k(
    const float* __restrict__ nl,
    const float* __restrict__ W1, const float* __restrict__ b1,
    const float* __restrict__ W2, const float* __restrict__ b2,
    float* __restrict__ out)
{
    constexpr int NPB = 16;
    __shared__ __align__(16) float xs[NPB * LNUM];
    __shared__ float hh[NPB * 8];
    const int t = threadIdx.x;
    const int base = blockIdx.x * NPB;
    for (int r = 0; r < NPB; r++) xs[r * LNUM + t] = nl[(base + r) * LNUM + t];
    __syncthreads();
    {
        const int node = t >> 3, j = t & 7;       // 16 nodes x 8 hidden
        float a = b1[j];
        for (int k = 0; k < LNUM; k++) a = fmaf(xs[node * LNUM + k], W1[k * 8 + j], a);
        hh[node * 8 + j] = a / (1.f + expf(-a));  // Swish
    }
    __syncthreads();
    for (int idx = t; idx < NPB * 10; idx += 128) {
        const int node = idx / 10, c = idx % 10;
        float a = b2[c];
        #pragma unroll
        for (int j = 0; j < 8; j++) a = fmaf(hh[node * 8 + j], W2[j * 10 + c], a);
        const int tt = c >> 1, d = c & 1;
        out[(size_t)tt * (NNODES * 2) + (size_t)(base + node) * 2 + d] =
            a * (float)(tt + 1);
    }
}

__global__ __launch_bounds__(256) void zero_k(float* __restrict__ p, int n)
{
    const int i = blockIdx.x * 256 + threadIdx.x;
    if (i < n) p[i] = 0.f;
}

// ---------------------------------------------------------------------------
extern "C" void kernel_launch(void* const* d_in, const int* in_sizes, int n_in,
                              void* d_out, int out_size, void* d_ws, size_t ws_size,
                              hipStream_t stream) {
    const float* F[34];
    for (int i = 0; i < 34; i++) F[i] = (const float*)d_in[i];
    const int* senders   = (const int*)d_in[4];
    const int* receivers = (const int*)d_in[5];

    const size_t nN = (size_t)NNODES * LNUM;
    const size_t nE = (size_t)NEDGES * LNUM;
    float* nl   = (float*)d_ws;
    float* el   = nl + nN;
    float* aggr = el + nE;

    encode_nodes_k<<<NNODES / 4, 128, 0, stream>>>(
        F[2], F[3], F[1], F[6], F[7], F[8], F[9], F[10], F[11], nl);
    encode_edges_k<<<NEDGES / 4, 128, 0, stream>>>(
        F[0], F[2], senders, receivers,
        F[12], F[13], F[14], F[15], F[16], F[17], el);

    for (int s = 0; s < NSTEPS; s++) {
        zero_k<<<(NNODES * LNUM + 255) / 256, 256, 0, stream>>>(aggr, NNODES * LNUM);
        block_edge_k<<<NEDGES / 4, 128, 0, stream>>>(
            nl, el, aggr, senders, receivers,
            F[18] + (size_t)s * 3 * LNUM * LNUM, F[19] + s * LNUM,
            F[20] + (size_t)s * LNUM * LNUM,     F[21] + s * LNUM,
            F[22] + s * LNUM, F[23] + s * LNUM);
        block_node_k<<<NNODES / 4, 128, 0, stream>>>(
            nl, aggr,
            F[24] + (size_t)s * 2 * LNUM * LNUM, F[25] + s * LNUM,
            F[26] + (size_t)s * LNUM * LNUM,     F[27] + s * LNUM,
            F[28] + s * LNUM, F[29] + s * LNUM);
    }

    decode_k<<<NNODES / 16, 128, 0, stream>>>(
        nl, F[30], F[31], F[32], F[33], (float*)d_out);
}